// Round 7
// baseline (500.587 us; speedup 1.0000x reference)
//
#include <hip/hip_runtime.h>
#include <hip/hip_bf16.h>

#define HOPS 3
#define NA 50000
#define NP 100000
#define NIN 256
#define NHID 128
#define NOUT 64
#define CAP_A 64
#define CAP_P 40

typedef __attribute__((ext_vector_type(8))) short bf16x8;
typedef __attribute__((ext_vector_type(4))) float f32x4;
typedef unsigned short ushort_t;

__device__ inline short f2bf(float f) {
    __hip_bfloat16 h = __float2bfloat16(f);
    return *reinterpret_cast<short*>(&h);
}
__device__ inline float bf2f(unsigned short u) {
    unsigned v = ((unsigned)u) << 16;
    return __uint_as_float(v);
}

// async global -> LDS, 16 bytes per lane (linear dest: base + lane*16)
__device__ inline void gload16(const void* g, void* l) {
    __builtin_amdgcn_global_load_lds(
        (const __attribute__((address_space(1))) unsigned int*)g,
        (__attribute__((address_space(3))) unsigned int*)l, 16, 0, 0);
}

// ---------- all weight transposes+converts in one launch ----------
__global__ void prep_all(const float* __restrict__ W1_A, const float* __restrict__ W1_P,
                         const float* __restrict__ W2,
                         short* __restrict__ WtA, short* __restrict__ WtP,
                         short* __restrict__ Wt2)
{
    int idx = blockIdx.x * 256 + threadIdx.x;
    const int S1 = NHID * NIN;
    if (idx < S1) {
        int n = idx / NIN, k = idx - n * NIN;
        WtA[idx] = f2bf(W1_A[(size_t)k * NHID + n]);
    } else if (idx < 2 * S1) {
        int j = idx - S1;
        int n = j / NIN, k = j - n * NIN;
        WtP[j] = f2bf(W1_P[(size_t)k * NHID + n]);
    } else if (idx < 2 * S1 + NOUT * NHID) {
        int j = idx - 2 * S1;
        int n = j / NHID, k = j - n * NHID;
        Wt2[j] = f2bf(W2[(size_t)k * NOUT + n]);
    }
}

// ---------- merged projection: Cbf = bf16(relu(X @ W1 + b1)) for A and P ----------
// One barrier total. Stage full 64x256 tile as bf16 in LDS: 16 independent
// coalesced float4 loads/thread (per instr a wave reads one contiguous 1KB row),
// cvt + ds_write_b64 (2-way-free banks). Then 64 MFMA/wave, B-frags from L2.
// mfma_f32_16x16x32_bf16: A row=l&15,k=(l>>4)*8+j ; B col=l&15 ; D col=l&15,row=(l>>4)*4+j
__global__ __launch_bounds__(256) void proj_mfma(
        const float* __restrict__ xA, const float* __restrict__ xP,
        const short* __restrict__ WtA_, const short* __restrict__ WtP_,
        const float* __restrict__ bA, const float* __restrict__ bP,
        ushort_t* __restrict__ CA, ushort_t* __restrict__ CP, int gA)
{
    __shared__ ushort_t Ab[64][264];   // 33.8KB, 528B row stride (16B aligned)
    const int tid = threadIdx.x;
    const int wv = tid >> 6, l = tid & 63;
    const int fl = l & 15, kg = l >> 4;

    const int bid = blockIdx.x;
    const bool isA = bid < gA;
    const float* X = isA ? xA : xP;
    const short* Wt = isA ? WtA_ : WtP_;
    const float* bias = isA ? bA : bP;
    ushort_t* C = isA ? CA : CP;
    const int M = isA ? NA : NP;
    const int Rbase = (isA ? bid : bid - gA) * 64;

    const int colf = l * 4;   // 4 f32 columns per lane per row

    #pragma unroll
    for (int half = 0; half < 2; ++half) {
        float4 v[8];
        #pragma unroll
        for (int i = 0; i < 8; ++i) {
            int rr = (half * 8 + i) * 4 + wv;
            int grr = Rbase + rr; if (grr >= M) grr = M - 1;
            v[i] = *(const float4*)(X + (size_t)grr * NIN + colf);
        }
        #pragma unroll
        for (int i = 0; i < 8; ++i) {
            int rr = (half * 8 + i) * 4 + wv;
            union { ushort_t u[4]; int2 q; } pk;
            pk.u[0] = (ushort_t)f2bf(v[i].x);
            pk.u[1] = (ushort_t)f2bf(v[i].y);
            pk.u[2] = (ushort_t)f2bf(v[i].z);
            pk.u[3] = (ushort_t)f2bf(v[i].w);
            *(int2*)&Ab[rr][colf] = pk.q;
        }
    }
    __syncthreads();

    f32x4 acc[8];
    #pragma unroll
    for (int c = 0; c < 8; ++c) acc[c] = (f32x4){0.f, 0.f, 0.f, 0.f};

    #pragma unroll
    for (int ks = 0; ks < 8; ++ks) {
        bf16x8 af = *(const bf16x8*)&Ab[wv * 16 + fl][ks * 32 + kg * 8];
        #pragma unroll
        for (int c = 0; c < 8; ++c) {
            bf16x8 bfr = *(const bf16x8*)(Wt + (size_t)(c * 16 + fl) * NIN
                                          + ks * 32 + kg * 8);
            acc[c] = __builtin_amdgcn_mfma_f32_16x16x32_bf16(af, bfr, acc[c], 0, 0, 0);
        }
    }

    #pragma unroll
    for (int c = 0; c < 8; ++c) {
        int col = c * 16 + fl;
        float bb = bias[col];
        #pragma unroll
        for (int j = 0; j < 4; ++j) {
            int grow = Rbase + wv * 16 + kg * 4 + j;
            if (grow < M) {
                float v = fmaxf(acc[c][j] + bb, 0.f);
                C[(size_t)grow * NHID + col] = (ushort_t)f2bf(v);
            }
        }
    }
}

// ---------- output: C[M,64] = Abf[M,128] @ W2 + b2, single-stage MFMA ----------
__global__ __launch_bounds__(256) void out_mfma(const ushort_t* __restrict__ Abf,
        const short* __restrict__ Wt, const float* __restrict__ b,
        float* __restrict__ C, int M)
{
    __shared__ ushort_t Sb[64 * 128];   // 16KB
    const int tid = threadIdx.x;
    const int wv = tid >> 6, l = tid & 63;
    const int fl = l & 15, kg = l >> 4;
    const int br = blockIdx.x * 64;
    const int srow = l >> 4, schk = l & 15;

    #pragma unroll
    for (int i = 0; i < 4; ++i) {
        int r = (wv * 4 + i) * 4 + srow;
        int gr = br + r; if (gr >= M) gr = M - 1;
        int ck = (schk ^ (r & 7)) * 8;
        gload16(Abf + (size_t)gr * NHID + ck, &Sb[(wv * 4 + i) * 512]);
    }

    f32x4 acc[4];
    #pragma unroll
    for (int c = 0; c < 4; ++c) acc[c] = (f32x4){0.f, 0.f, 0.f, 0.f};

    bf16x8 Bf[16];
    #pragma unroll
    for (int ks = 0; ks < 4; ++ks)
        #pragma unroll
        for (int cc = 0; cc < 4; ++cc)
            Bf[ks * 4 + cc] = *(const bf16x8*)(Wt + (size_t)(cc * 16 + fl) * NHID
                                               + ks * 32 + kg * 8);
    __syncthreads();

    const int R = wv * 16 + fl;
    const int rx = R & 7;
    #pragma unroll
    for (int ks = 0; ks < 4; ++ks) {
        int chunk = (ks * 4 + kg) ^ rx;
        bf16x8 af = *(const bf16x8*)&Sb[R * 128 + chunk * 8];
        #pragma unroll
        for (int cc = 0; cc < 4; ++cc)
            acc[cc] = __builtin_amdgcn_mfma_f32_16x16x32_bf16(af, Bf[ks * 4 + cc],
                                                              acc[cc], 0, 0, 0);
    }

    #pragma unroll
    for (int cc = 0; cc < 4; ++cc) {
        int col = cc * 16 + fl;
        float bb = b[col];
        #pragma unroll
        for (int j = 0; j < 4; ++j) {
            int grow = br + wv * 16 + kg * 4 + j;
            if (grow < M) C[(size_t)grow * NOUT + col] = acc[cc][j] + bb;
        }
    }
}

// ---------- merged padded-CSR fill ----------
__global__ void fill_kernel(const int* __restrict__ sA, const int* __restrict__ tA,
                            const int* __restrict__ sP, const int* __restrict__ tP,
                            int* __restrict__ cntA, int* __restrict__ slotsA,
                            int* __restrict__ cntP, int* __restrict__ slotsP, int nE)
{
    int e = blockIdx.x * 256 + threadIdx.x;
    if (e < nE) {
        int si = sA[e];
        int c = atomicAdd(&cntA[si], 1);
        if (c < CAP_A) slotsA[(size_t)si * CAP_A + c] = tA[e];
    } else if (e < 2 * nE) {
        int k = e - nE;
        int si = sP[k];
        int c = atomicAdd(&cntP[si], 1);
        if (c < CAP_P) slotsP[(size_t)si * CAP_P + c] = tP[k];
    }
}

// ---------- merged x-side scalars for ALL hops ----------
__global__ void xdots_kernel(const ushort_t* __restrict__ xAbf, const ushort_t* __restrict__ xPbf,
                             const float* __restrict__ attn1, const float* __restrict__ attn2,
                             float* __restrict__ x1A, float* __restrict__ w2A, float* __restrict__ h1Ai,
                             float* __restrict__ x1P, float* __restrict__ w2P, float* __restrict__ h1Pi)
{
    int wid = (blockIdx.x * blockDim.x + threadIdx.x) >> 6;
    int lane = threadIdx.x & 63;
    if (wid >= NA + NP) return;
    bool isA = wid < NA;
    int n = isA ? wid : wid - NA;
    int etype = isA ? 0 : 1;
    const ushort_t* x = (isA ? xAbf : xPbf) + (size_t)n * NHID;
    ushort2 xv = *(const ushort2*)(x + lane * 2);
    float xa = bf2f(xv.x), xb = bf2f(xv.y);
    float s[7];
    #pragma unroll
    for (int i = 0; i < 3; ++i) {
        float2 a1v = *(const float2*)(attn1 + (size_t)(i * 2 + etype) * NHID + lane * 2);
        float2 a2v = *(const float2*)(attn2 + (size_t)(i * 2 + etype) * NHID + lane * 2);
        s[i]     = xa * a1v.x + xb * a1v.y;
        s[3 + i] = xa * a2v.x + xb * a2v.y;
    }
    float2 a2o = *(const float2*)(attn2 + (size_t)(1 - etype) * NHID + lane * 2);
    s[6] = xa * a2o.x + xb * a2o.y;
    #pragma unroll
    for (int m = 32; m; m >>= 1)
        #pragma unroll
        for (int i = 0; i < 7; ++i) s[i] += __shfl_xor(s[i], m, 64);
    if (lane == 0) {
        int N = isA ? NA : NP;
        float* x1 = isA ? x1A : x1P;
        float* w2 = isA ? w2A : w2P;
        #pragma unroll
        for (int i = 0; i < 3; ++i) {
            x1[(size_t)i * N + n] = s[i];
            float v = s[i] + s[3 + i];
            v = v > 0.f ? v : 0.2f * v;
            w2[(size_t)i * N + n] = __expf(v);
        }
        (isA ? h1Ai : h1Pi)[n] = s[6];
    }
}

// ---------- fused A+P aggregation, wave-cooperative score preload ----------
// Lane l preloads slot l (one coalesced 256B read), h1[t_l] (64 parallel
// random 4B loads) and w_l = exp(leaky(.)). Rounds then shfl-broadcast (t,w)
// per 8-lane group and do row-gather + fma with one-round-ahead prefetch.
__global__ __launch_bounds__(256) void agg_fused(
    const ushort_t* __restrict__ xAbf, const ushort_t* __restrict__ xPbf,
    const ushort_t* __restrict__ hAg, const ushort_t* __restrict__ hPg,
    const float* __restrict__ x1Ah, const float* __restrict__ x1Ph,
    const float* __restrict__ w2Ah, const float* __restrict__ w2Ph,
    const float* __restrict__ h1Agc, const float* __restrict__ h1Pgc,
    const int* __restrict__ cntA, const int* __restrict__ slotsA,
    const int* __restrict__ cntP, const int* __restrict__ slotsP,
    const float* __restrict__ a2nA, const float* __restrict__ a2nP,
    ushort_t* __restrict__ hAout, ushort_t* __restrict__ hPout,
    float* __restrict__ h1Aout, float* __restrict__ h1Pout,
    int nodes)
{
    int wid = (blockIdx.x * blockDim.x + threadIdx.x) >> 6;
    int lane = threadIdx.x & 63;
    if (wid >= nodes) return;
    int g = lane >> 3, fl = lane & 7;
    bool isA = wid < NA;
    int n = isA ? wid : wid - NA;
    int deg; const int* sl; const ushort_t* hbf; const float* h1g; float x1v;
    if (isA) {
        deg = cntA[n]; if (deg > CAP_A) deg = CAP_A;
        sl = slotsA + (size_t)n * CAP_A; hbf = hPg; h1g = h1Pgc; x1v = x1Ah[n];
    } else {
        deg = cntP[n]; if (deg > CAP_P) deg = CAP_P;
        sl = slotsP + (size_t)n * CAP_P; hbf = hAg; h1g = h1Agc; x1v = x1Ph[n];
    }

    // cooperative preload of all edge scalars
    int t_l = 0;
    float w_l = 0.f;
    if (deg > 0) {
        int idx = lane < deg ? lane : deg - 1;
        t_l = sl[idx];
        if (lane < deg) {
            float v = x1v + h1g[t_l];
            v = v > 0.f ? v : 0.2f * v;
            w_l = __expf(v);
        }
    }
    float div = w_l;                 // full-wave reduce below counts each edge once
    float acc[16] = {};
    int R = (deg + 7) >> 3;

    int4 ra = {0, 0, 0, 0}, rb = {0, 0, 0, 0};
    if (R > 0) {
        int t0 = __shfl(t_l, g, 64);
        const int4* p = (const int4*)(hbf + (size_t)t0 * NHID + fl * 16);
        ra = p[0]; rb = p[1];
    }
    for (int r = 0; r < R; ++r) {
        float w = __shfl(w_l, r * 8 + g, 64);
        int4 ca = ra, cb = rb;
        if (r + 1 < R) {
            int tn = __shfl(t_l, (r + 1) * 8 + g, 64);
            const int4* pn = (const int4*)(hbf + (size_t)tn * NHID + fl * 16);
            ra = pn[0]; rb = pn[1];
        }
        union { int4 v; ushort_t u[8]; } a;
        a.v = ca;
        #pragma unroll
        for (int j = 0; j < 8; ++j) acc[j] += w * bf2f(a.u[j]);
        a.v = cb;
        #pragma unroll
        for (int j = 0; j < 8; ++j) acc[8 + j] += w * bf2f(a.u[j]);
    }

    #pragma unroll
    for (int m = 8; m <= 32; m <<= 1) {
        #pragma unroll
        for (int j = 0; j < 16; ++j) acc[j] += __shfl_xor(acc[j], m, 64);
    }
    #pragma unroll
    for (int m = 1; m <= 32; m <<= 1) div += __shfl_xor(div, m, 64);

    if (g == 0) {
        float w2v = isA ? w2Ah[n] : w2Ph[n];
        const ushort_t* xb = (isA ? xAbf : xPbf) + (size_t)n * NHID + fl * 16;
        union { int4 v; ushort_t u[8]; } x0, x1u;
        x0.v = ((const int4*)xb)[0];
        x1u.v = ((const int4*)xb)[1];
        #pragma unroll
        for (int j = 0; j < 8; ++j) {
            acc[j] += w2v * bf2f(x0.u[j]);
            acc[8 + j] += w2v * bf2f(x1u.u[j]);
        }
        div += w2v;
        float inv = 1.f / div;
        const float* a2 = isA ? a2nA : a2nP;
        float s = 0.f;
        float o[16];
        #pragma unroll
        for (int j = 0; j < 16; ++j) {
            float v = acc[j] * inv;
            o[j] = v > 0.f ? v : (__expf(v) - 1.f);
            s += o[j] * a2[fl * 16 + j];
        }
        s += __shfl_xor(s, 1, 64);
        s += __shfl_xor(s, 2, 64);
        s += __shfl_xor(s, 4, 64);
        ushort_t* hb = (isA ? hAout : hPout) + (size_t)n * NHID + fl * 16;
        union { ushort_t u[8]; int4 v; } pk;
        #pragma unroll
        for (int j = 0; j < 8; ++j) pk.u[j] = (ushort_t)f2bf(o[j]);
        ((int4*)hb)[0] = pk.v;
        #pragma unroll
        for (int j = 0; j < 8; ++j) pk.u[j] = (ushort_t)f2bf(o[8 + j]);
        ((int4*)hb)[1] = pk.v;
        if (fl == 0) (isA ? h1Aout : h1Pout)[n] = s;
    }
}

extern "C" void kernel_launch(void* const* d_in, const int* in_sizes, int n_in,
                              void* d_out, int out_size, void* d_ws, size_t ws_size,
                              hipStream_t stream)
{
    const float* x_A  = (const float*)d_in[0];
    const float* x_P  = (const float*)d_in[1];
    const int*   sAP  = (const int*)d_in[2];
    const int*   tAP  = (const int*)d_in[3];
    const int*   sPA  = (const int*)d_in[4];
    const int*   tPA  = (const int*)d_in[5];
    const float* W1_A = (const float*)d_in[6];
    const float* b1_A = (const float*)d_in[7];
    const float* W1_P = (const float*)d_in[8];
    const float* b1_P = (const float*)d_in[9];
    const float* attn1 = (const float*)d_in[10];
    const float* attn2 = (const float*)d_in[11];
    const float* W2   = (const float*)d_in[12];
    const float* b2   = (const float*)d_in[13];
    float* out = (float*)d_out;
    int nE = in_sizes[2];

    char* ws = (char*)d_ws;
    size_t off = 0;
    auto alloc = [&](size_t bytes) -> void* {
        void* p = ws + off;
        off += (bytes + 255) & ~(size_t)255;
        return p;
    };
    ushort_t* xAbf  = (ushort_t*)alloc((size_t)NA * NHID * 2);
    ushort_t* xPbf  = (ushort_t*)alloc((size_t)NP * NHID * 2);
    ushort_t* hAbf[2] = {(ushort_t*)alloc((size_t)NA * NHID * 2),
                         (ushort_t*)alloc((size_t)NA * NHID * 2)};
    ushort_t* hPbf[2] = {(ushort_t*)alloc((size_t)NP * NHID * 2),
                         (ushort_t*)alloc((size_t)NP * NHID * 2)};
    float* x1A = (float*)alloc((size_t)3 * NA * 4);
    float* w2A = (float*)alloc((size_t)3 * NA * 4);
    float* x1P = (float*)alloc((size_t)3 * NP * 4);
    float* w2P = (float*)alloc((size_t)3 * NP * 4);
    float* h1Ai = (float*)alloc(NA * 4);
    float* h1Pi = (float*)alloc(NP * 4);
    float* h1Ab[2] = {(float*)alloc(NA * 4), (float*)alloc(NA * 4)};
    float* h1Pb[2] = {(float*)alloc(NP * 4), (float*)alloc(NP * 4)};
    int* cntA  = (int*)alloc(NA * 4);
    int* cntP  = (int*)alloc(NP * 4);
    int* slotsA = (int*)alloc((size_t)NA * CAP_A * 4);
    int* slotsP = (int*)alloc((size_t)NP * CAP_P * 4);
    short* WtA = (short*)alloc((size_t)NHID * NIN * 2);
    short* WtP = (short*)alloc((size_t)NHID * NIN * 2);
    short* Wt2 = (short*)alloc((size_t)NOUT * NHID * 2);

    // padded CSR (edge structure reused by all hops)
    hipMemsetAsync(cntA, 0, NA * 4, stream);
    hipMemsetAsync(cntP, 0, NP * 4, stream);
    fill_kernel<<<(2 * nE + 255) / 256, 256, 0, stream>>>(sAP, tAP, sPA, tPA,
                                                          cntA, slotsA, cntP, slotsP, nE);

    // weights -> bf16 transposed (one launch)
    prep_all<<<(2 * NHID * NIN + NOUT * NHID + 255) / 256, 256, 0, stream>>>(
        W1_A, W1_P, W2, WtA, WtP, Wt2);

    // merged projections -> bf16 h0
    int gA = (NA + 63) / 64, gP = (NP + 63) / 64;
    proj_mfma<<<gA + gP, 256, 0, stream>>>(x_A, x_P, WtA, WtP, b1_A, b1_P,
                                           xAbf, xPbf, gA);

    // x-side scalars for all hops (merged)
    xdots_kernel<<<(NA + NP + 3) / 4, 256, 0, stream>>>(
        xAbf, xPbf, attn1, attn2, x1A, w2A, h1Ai, x1P, w2P, h1Pi);

    const ushort_t* hAg = xAbf;
    const ushort_t* hPg = xPbf;
    const float* h1Ac = h1Ai;
    const float* h1Pc = h1Pi;

    for (int i = 0; i < HOPS; ++i) {
        int last = (i == HOPS - 1);
        int nodes = last ? NA : (NA + NP);
        const float* a2nA_ = last ? attn2 : attn2 + (size_t)((i + 1) * 2 + 1) * NHID;
        const float* a2nP_ = last ? attn2 : attn2 + (size_t)((i + 1) * 2 + 0) * NHID;
        agg_fused<<<(nodes + 3) / 4, 256, 0, stream>>>(
            xAbf, xPbf, hAg, hPg,
            x1A + (size_t)i * NA, x1P + (size_t)i * NP,
            w2A + (size_t)i * NA, w2P + (size_t)i * NP,
            h1Ac, h1Pc,
            cntA, slotsA, cntP, slotsP,
            a2nA_, a2nP_,
            hAbf[i & 1], hPbf[i & 1], h1Ab[i & 1], h1Pb[i & 1],
            nodes);
        hAg = hAbf[i & 1]; hPg = hPbf[i & 1];
        h1Ac = h1Ab[i & 1]; h1Pc = h1Pb[i & 1];
    }

    out_mfma<<<(NA + 63) / 64, 256, 0, stream>>>(hAg, Wt2, b2, out, NA);
}

// Round 8
// 453.644 us; speedup vs baseline: 1.1035x; 1.1035x over previous
//
#include <hip/hip_runtime.h>
#include <hip/hip_bf16.h>

#define HOPS 3
#define NA 50000
#define NP 100000
#define NIN 256
#define NHID 128
#define NOUT 64
#define CAP_A 64
#define CAP_P 40

typedef __attribute__((ext_vector_type(8))) short bf16x8;
typedef __attribute__((ext_vector_type(4))) float f32x4;
typedef unsigned short ushort_t;

__device__ inline short f2bf(float f) {
    __hip_bfloat16 h = __float2bfloat16(f);
    return *reinterpret_cast<short*>(&h);
}
__device__ inline float bf2f(unsigned short u) {
    unsigned v = ((unsigned)u) << 16;
    return __uint_as_float(v);
}

// async global -> LDS, 16 bytes per lane (linear dest: base + lane*16)
__device__ inline void gload16(const void* g, void* l) {
    __builtin_amdgcn_global_load_lds(
        (const __attribute__((address_space(1))) unsigned int*)g,
        (__attribute__((address_space(3))) unsigned int*)l, 16, 0, 0);
}

// ---------- all weight transposes+converts in one launch ----------
__global__ void prep_all(const float* __restrict__ W1_A, const float* __restrict__ W1_P,
                         const float* __restrict__ W2,
                         short* __restrict__ WtA, short* __restrict__ WtP,
                         short* __restrict__ Wt2)
{
    int idx = blockIdx.x * 256 + threadIdx.x;
    const int S1 = NHID * NIN;
    if (idx < S1) {
        int n = idx / NIN, k = idx - n * NIN;
        WtA[idx] = f2bf(W1_A[(size_t)k * NHID + n]);
    } else if (idx < 2 * S1) {
        int j = idx - S1;
        int n = j / NIN, k = j - n * NIN;
        WtP[j] = f2bf(W1_P[(size_t)k * NHID + n]);
    } else if (idx < 2 * S1 + NOUT * NHID) {
        int j = idx - 2 * S1;
        int n = j / NHID, k = j - n * NHID;
        Wt2[j] = f2bf(W2[(size_t)k * NOUT + n]);
    }
}

// ---------- projection (round-2 measured-best structure): ----------
// Cbf[M,128] = bf16(relu(A[M,256] @ W + b)). 256 thr / 4 waves, tile 64x128,
// BK=32, BOTH A-tile (f32->bf16 at stage) and Wt-tile staged in padded LDS
// (stride 40 shorts), 2 barriers per K-step.
// mfma_f32_16x16x32_bf16: A row=l&15,k=(l>>4)*8+j ; B col=l&15 ; D col=l&15,row=(l>>4)*4+j
__global__ __launch_bounds__(256) void proj_mfma(const float* __restrict__ A,
                                                 const short* __restrict__ Wt,
                                                 const float* __restrict__ b,
                                                 ushort_t* __restrict__ Cbf, int M)
{
    __shared__ short Alds[64][40];    // stride 80B: 16B-aligned, 2-way-free banks
    __shared__ short Wlds[128][40];
    int tid = threadIdx.x;
    int br = blockIdx.x * 64;
    int wv = tid >> 6;
    int l = tid & 63;
    int fl = l & 15;
    int kg = l >> 4;

    // staging indices
    int sr = tid >> 2;            // 0..63 row
    int skp = (tid & 3) * 8;      // k-part 0/8/16/24
    int sgr = br + sr; if (sgr >= M) sgr = M - 1;
    int sn = tid >> 1;            // 0..127 col of Wt
    int skq = (tid & 1) * 16;     // 0/16

    f32x4 acc[8];
    #pragma unroll
    for (int c = 0; c < 8; ++c) acc[c] = (f32x4){0.f, 0.f, 0.f, 0.f};

    for (int k0 = 0; k0 < NIN; k0 += 32) {
        // stage A tile 64x32 (f32 -> bf16)
        const float4* ap = (const float4*)(A + (size_t)sgr * NIN + k0 + skp);
        float4 v0 = ap[0], v1 = ap[1];
        union { short s[8]; int4 v; } pk;
        pk.s[0] = f2bf(v0.x); pk.s[1] = f2bf(v0.y);
        pk.s[2] = f2bf(v0.z); pk.s[3] = f2bf(v0.w);
        pk.s[4] = f2bf(v1.x); pk.s[5] = f2bf(v1.y);
        pk.s[6] = f2bf(v1.z); pk.s[7] = f2bf(v1.w);
        *(int4*)&Alds[sr][skp] = pk.v;
        // stage Wt tile 128x32 (bf16 copy)
        const int4* wp = (const int4*)(Wt + (size_t)sn * NIN + k0 + skq);
        int4 w0 = wp[0], w1 = wp[1];
        *(int4*)&Wlds[sn][skq] = w0;
        *(int4*)&Wlds[sn][skq + 8] = w1;
        __syncthreads();

        bf16x8 afr = *(bf16x8*)&Alds[wv * 16 + fl][kg * 8];
        #pragma unroll
        for (int c = 0; c < 8; ++c) {
            bf16x8 bfr = *(bf16x8*)&Wlds[c * 16 + fl][kg * 8];
            acc[c] = __builtin_amdgcn_mfma_f32_16x16x32_bf16(afr, bfr, acc[c], 0, 0, 0);
        }
        __syncthreads();
    }

    int rj = kg * 4;
    #pragma unroll
    for (int c = 0; c < 8; ++c) {
        int col = c * 16 + fl;
        float bb = b[col];
        #pragma unroll
        for (int j = 0; j < 4; ++j) {
            int grow = br + wv * 16 + rj + j;
            if (grow < M) {
                float v = fmaxf(acc[c][j] + bb, 0.f);
                Cbf[(size_t)grow * NHID + col] = (ushort_t)f2bf(v);
            }
        }
    }
}

// ---------- output: C[M,64] = Abf[M,128] @ W2 + b2, single-stage MFMA ----------
__global__ __launch_bounds__(256) void out_mfma(const ushort_t* __restrict__ Abf,
        const short* __restrict__ Wt, const float* __restrict__ b,
        float* __restrict__ C, int M)
{
    __shared__ ushort_t Sb[64 * 128];   // 16KB
    const int tid = threadIdx.x;
    const int wv = tid >> 6, l = tid & 63;
    const int fl = l & 15, kg = l >> 4;
    const int br = blockIdx.x * 64;
    const int srow = l >> 4, schk = l & 15;

    #pragma unroll
    for (int i = 0; i < 4; ++i) {
        int r = (wv * 4 + i) * 4 + srow;
        int gr = br + r; if (gr >= M) gr = M - 1;
        int ck = (schk ^ (r & 7)) * 8;
        gload16(Abf + (size_t)gr * NHID + ck, &Sb[(wv * 4 + i) * 512]);
    }

    f32x4 acc[4];
    #pragma unroll
    for (int c = 0; c < 4; ++c) acc[c] = (f32x4){0.f, 0.f, 0.f, 0.f};

    bf16x8 Bf[16];
    #pragma unroll
    for (int ks = 0; ks < 4; ++ks)
        #pragma unroll
        for (int cc = 0; cc < 4; ++cc)
            Bf[ks * 4 + cc] = *(const bf16x8*)(Wt + (size_t)(cc * 16 + fl) * NHID
                                               + ks * 32 + kg * 8);
    __syncthreads();

    const int R = wv * 16 + fl;
    const int rx = R & 7;
    #pragma unroll
    for (int ks = 0; ks < 4; ++ks) {
        int chunk = (ks * 4 + kg) ^ rx;
        bf16x8 af = *(const bf16x8*)&Sb[R * 128 + chunk * 8];
        #pragma unroll
        for (int cc = 0; cc < 4; ++cc)
            acc[cc] = __builtin_amdgcn_mfma_f32_16x16x32_bf16(af, Bf[ks * 4 + cc],
                                                              acc[cc], 0, 0, 0);
    }

    #pragma unroll
    for (int cc = 0; cc < 4; ++cc) {
        int col = cc * 16 + fl;
        float bb = b[col];
        #pragma unroll
        for (int j = 0; j < 4; ++j) {
            int grow = br + wv * 16 + kg * 4 + j;
            if (grow < M) C[(size_t)grow * NOUT + col] = acc[cc][j] + bb;
        }
    }
}

// ---------- merged padded-CSR fill ----------
__global__ void fill_kernel(const int* __restrict__ sA, const int* __restrict__ tA,
                            const int* __restrict__ sP, const int* __restrict__ tP,
                            int* __restrict__ cntA, int* __restrict__ slotsA,
                            int* __restrict__ cntP, int* __restrict__ slotsP, int nE)
{
    int e = blockIdx.x * 256 + threadIdx.x;
    if (e < nE) {
        int si = sA[e];
        int c = atomicAdd(&cntA[si], 1);
        if (c < CAP_A) slotsA[(size_t)si * CAP_A + c] = tA[e];
    } else if (e < 2 * nE) {
        int k = e - nE;
        int si = sP[k];
        int c = atomicAdd(&cntP[si], 1);
        if (c < CAP_P) slotsP[(size_t)si * CAP_P + c] = tP[k];
    }
}

// ---------- merged x-side scalars for ALL hops ----------
__global__ void xdots_kernel(const ushort_t* __restrict__ xAbf, const ushort_t* __restrict__ xPbf,
                             const float* __restrict__ attn1, const float* __restrict__ attn2,
                             float* __restrict__ x1A, float* __restrict__ w2A, float* __restrict__ h1Ai,
                             float* __restrict__ x1P, float* __restrict__ w2P, float* __restrict__ h1Pi)
{
    int wid = (blockIdx.x * blockDim.x + threadIdx.x) >> 6;
    int lane = threadIdx.x & 63;
    if (wid >= NA + NP) return;
    bool isA = wid < NA;
    int n = isA ? wid : wid - NA;
    int etype = isA ? 0 : 1;
    const ushort_t* x = (isA ? xAbf : xPbf) + (size_t)n * NHID;
    ushort2 xv = *(const ushort2*)(x + lane * 2);
    float xa = bf2f(xv.x), xb = bf2f(xv.y);
    float s[7];
    #pragma unroll
    for (int i = 0; i < 3; ++i) {
        float2 a1v = *(const float2*)(attn1 + (size_t)(i * 2 + etype) * NHID + lane * 2);
        float2 a2v = *(const float2*)(attn2 + (size_t)(i * 2 + etype) * NHID + lane * 2);
        s[i]     = xa * a1v.x + xb * a1v.y;
        s[3 + i] = xa * a2v.x + xb * a2v.y;
    }
    float2 a2o = *(const float2*)(attn2 + (size_t)(1 - etype) * NHID + lane * 2);
    s[6] = xa * a2o.x + xb * a2o.y;
    #pragma unroll
    for (int m = 32; m; m >>= 1)
        #pragma unroll
        for (int i = 0; i < 7; ++i) s[i] += __shfl_xor(s[i], m, 64);
    if (lane == 0) {
        int N = isA ? NA : NP;
        float* x1 = isA ? x1A : x1P;
        float* w2 = isA ? w2A : w2P;
        #pragma unroll
        for (int i = 0; i < 3; ++i) {
            x1[(size_t)i * N + n] = s[i];
            float v = s[i] + s[3 + i];
            v = v > 0.f ? v : 0.2f * v;
            w2[(size_t)i * N + n] = __expf(v);
        }
        (isA ? h1Ai : h1Pi)[n] = s[6];
    }
}

// ---------- fused A+P aggregation, wave-cooperative score preload ----------
__global__ __launch_bounds__(256) void agg_fused(
    const ushort_t* __restrict__ xAbf, const ushort_t* __restrict__ xPbf,
    const ushort_t* __restrict__ hAg, const ushort_t* __restrict__ hPg,
    const float* __restrict__ x1Ah, const float* __restrict__ x1Ph,
    const float* __restrict__ w2Ah, const float* __restrict__ w2Ph,
    const float* __restrict__ h1Agc, const float* __restrict__ h1Pgc,
    const int* __restrict__ cntA, const int* __restrict__ slotsA,
    const int* __restrict__ cntP, const int* __restrict__ slotsP,
    const float* __restrict__ a2nA, const float* __restrict__ a2nP,
    ushort_t* __restrict__ hAout, ushort_t* __restrict__ hPout,
    float* __restrict__ h1Aout, float* __restrict__ h1Pout,
    int nodes)
{
    int wid = (blockIdx.x * blockDim.x + threadIdx.x) >> 6;
    int lane = threadIdx.x & 63;
    if (wid >= nodes) return;
    int g = lane >> 3, fl = lane & 7;
    bool isA = wid < NA;
    int n = isA ? wid : wid - NA;
    int deg; const int* sl; const ushort_t* hbf; const float* h1g; float x1v;
    if (isA) {
        deg = cntA[n]; if (deg > CAP_A) deg = CAP_A;
        sl = slotsA + (size_t)n * CAP_A; hbf = hPg; h1g = h1Pgc; x1v = x1Ah[n];
    } else {
        deg = cntP[n]; if (deg > CAP_P) deg = CAP_P;
        sl = slotsP + (size_t)n * CAP_P; hbf = hAg; h1g = h1Agc; x1v = x1Ph[n];
    }

    // cooperative preload of all edge scalars
    int t_l = 0;
    float w_l = 0.f;
    if (deg > 0) {
        int idx = lane < deg ? lane : deg - 1;
        t_l = sl[idx];
        if (lane < deg) {
            float v = x1v + h1g[t_l];
            v = v > 0.f ? v : 0.2f * v;
            w_l = __expf(v);
        }
    }
    float div = w_l;
    float acc[16] = {};
    int R = (deg + 7) >> 3;

    int4 ra = {0, 0, 0, 0}, rb = {0, 0, 0, 0};
    if (R > 0) {
        int t0 = __shfl(t_l, g, 64);
        const int4* p = (const int4*)(hbf + (size_t)t0 * NHID + fl * 16);
        ra = p[0]; rb = p[1];
    }
    for (int r = 0; r < R; ++r) {
        float w = __shfl(w_l, r * 8 + g, 64);
        int4 ca = ra, cb = rb;
        if (r + 1 < R) {
            int tn = __shfl(t_l, (r + 1) * 8 + g, 64);
            const int4* pn = (const int4*)(hbf + (size_t)tn * NHID + fl * 16);
            ra = pn[0]; rb = pn[1];
        }
        union { int4 v; ushort_t u[8]; } a;
        a.v = ca;
        #pragma unroll
        for (int j = 0; j < 8; ++j) acc[j] += w * bf2f(a.u[j]);
        a.v = cb;
        #pragma unroll
        for (int j = 0; j < 8; ++j) acc[8 + j] += w * bf2f(a.u[j]);
    }

    #pragma unroll
    for (int m = 8; m <= 32; m <<= 1) {
        #pragma unroll
        for (int j = 0; j < 16; ++j) acc[j] += __shfl_xor(acc[j], m, 64);
    }
    #pragma unroll
    for (int m = 1; m <= 32; m <<= 1) div += __shfl_xor(div, m, 64);

    if (g == 0) {
        float w2v = isA ? w2Ah[n] : w2Ph[n];
        const ushort_t* xb = (isA ? xAbf : xPbf) + (size_t)n * NHID + fl * 16;
        union { int4 v; ushort_t u[8]; } x0, x1u;
        x0.v = ((const int4*)xb)[0];
        x1u.v = ((const int4*)xb)[1];
        #pragma unroll
        for (int j = 0; j < 8; ++j) {
            acc[j] += w2v * bf2f(x0.u[j]);
            acc[8 + j] += w2v * bf2f(x1u.u[j]);
        }
        div += w2v;
        float inv = 1.f / div;
        const float* a2 = isA ? a2nA : a2nP;
        float s = 0.f;
        float o[16];
        #pragma unroll
        for (int j = 0; j < 16; ++j) {
            float v = acc[j] * inv;
            o[j] = v > 0.f ? v : (__expf(v) - 1.f);
            s += o[j] * a2[fl * 16 + j];
        }
        s += __shfl_xor(s, 1, 64);
        s += __shfl_xor(s, 2, 64);
        s += __shfl_xor(s, 4, 64);
        ushort_t* hb = (isA ? hAout : hPout) + (size_t)n * NHID + fl * 16;
        union { ushort_t u[8]; int4 v; } pk;
        #pragma unroll
        for (int j = 0; j < 8; ++j) pk.u[j] = (ushort_t)f2bf(o[j]);
        ((int4*)hb)[0] = pk.v;
        #pragma unroll
        for (int j = 0; j < 8; ++j) pk.u[j] = (ushort_t)f2bf(o[8 + j]);
        ((int4*)hb)[1] = pk.v;
        if (fl == 0) (isA ? h1Aout : h1Pout)[n] = s;
    }
}

extern "C" void kernel_launch(void* const* d_in, const int* in_sizes, int n_in,
                              void* d_out, int out_size, void* d_ws, size_t ws_size,
                              hipStream_t stream)
{
    const float* x_A  = (const float*)d_in[0];
    const float* x_P  = (const float*)d_in[1];
    const int*   sAP  = (const int*)d_in[2];
    const int*   tAP  = (const int*)d_in[3];
    const int*   sPA  = (const int*)d_in[4];
    const int*   tPA  = (const int*)d_in[5];
    const float* W1_A = (const float*)d_in[6];
    const float* b1_A = (const float*)d_in[7];
    const float* W1_P = (const float*)d_in[8];
    const float* b1_P = (const float*)d_in[9];
    const float* attn1 = (const float*)d_in[10];
    const float* attn2 = (const float*)d_in[11];
    const float* W2   = (const float*)d_in[12];
    const float* b2   = (const float*)d_in[13];
    float* out = (float*)d_out;
    int nE = in_sizes[2];

    char* ws = (char*)d_ws;
    size_t off = 0;
    auto alloc = [&](size_t bytes) -> void* {
        void* p = ws + off;
        off += (bytes + 255) & ~(size_t)255;
        return p;
    };
    ushort_t* xAbf  = (ushort_t*)alloc((size_t)NA * NHID * 2);
    ushort_t* xPbf  = (ushort_t*)alloc((size_t)NP * NHID * 2);
    ushort_t* hAbf[2] = {(ushort_t*)alloc((size_t)NA * NHID * 2),
                         (ushort_t*)alloc((size_t)NA * NHID * 2)};
    ushort_t* hPbf[2] = {(ushort_t*)alloc((size_t)NP * NHID * 2),
                         (ushort_t*)alloc((size_t)NP * NHID * 2)};
    float* x1A = (float*)alloc((size_t)3 * NA * 4);
    float* w2A = (float*)alloc((size_t)3 * NA * 4);
    float* x1P = (float*)alloc((size_t)3 * NP * 4);
    float* w2P = (float*)alloc((size_t)3 * NP * 4);
    float* h1Ai = (float*)alloc(NA * 4);
    float* h1Pi = (float*)alloc(NP * 4);
    float* h1Ab[2] = {(float*)alloc(NA * 4), (float*)alloc(NA * 4)};
    float* h1Pb[2] = {(float*)alloc(NP * 4), (float*)alloc(NP * 4)};
    int* cntA  = (int*)alloc(NA * 4);
    int* cntP  = (int*)alloc(NP * 4);
    int* slotsA = (int*)alloc((size_t)NA * CAP_A * 4);
    int* slotsP = (int*)alloc((size_t)NP * CAP_P * 4);
    short* WtA = (short*)alloc((size_t)NHID * NIN * 2);
    short* WtP = (short*)alloc((size_t)NHID * NIN * 2);
    short* Wt2 = (short*)alloc((size_t)NOUT * NHID * 2);

    // padded CSR (edge structure reused by all hops)
    hipMemsetAsync(cntA, 0, NA * 4, stream);
    hipMemsetAsync(cntP, 0, NP * 4, stream);
    fill_kernel<<<(2 * nE + 255) / 256, 256, 0, stream>>>(sAP, tAP, sPA, tPA,
                                                          cntA, slotsA, cntP, slotsP, nE);

    // weights -> bf16 transposed (one launch)
    prep_all<<<(2 * NHID * NIN + NOUT * NHID + 255) / 256, 256, 0, stream>>>(
        W1_A, W1_P, W2, WtA, WtP, Wt2);

    // projections -> bf16 h0 (round-2 measured-best structure, separate launches)
    proj_mfma<<<(NA + 63) / 64, 256, 0, stream>>>(x_A, WtA, b1_A, xAbf, NA);
    proj_mfma<<<(NP + 63) / 64, 256, 0, stream>>>(x_P, WtP, b1_P, xPbf, NP);

    // x-side scalars for all hops (merged)
    xdots_kernel<<<(NA + NP + 3) / 4, 256, 0, stream>>>(
        xAbf, xPbf, attn1, attn2, x1A, w2A, h1Ai, x1P, w2P, h1Pi);

    const ushort_t* hAg = xAbf;
    const ushort_t* hPg = xPbf;
    const float* h1Ac = h1Ai;
    const float* h1Pc = h1Pi;

    for (int i = 0; i < HOPS; ++i) {
        int last = (i == HOPS - 1);
        int nodes = last ? NA : (NA + NP);
        const float* a2nA_ = last ? attn2 : attn2 + (size_t)((i + 1) * 2 + 1) * NHID;
        const float* a2nP_ = last ? attn2 : attn2 + (size_t)((i + 1) * 2 + 0) * NHID;
        agg_fused<<<(nodes + 3) / 4, 256, 0, stream>>>(
            xAbf, xPbf, hAg, hPg,
            x1A + (size_t)i * NA, x1P + (size_t)i * NP,
            w2A + (size_t)i * NA, w2P + (size_t)i * NP,
            h1Ac, h1Pc,
            cntA, slotsA, cntP, slotsP,
            a2nA_, a2nP_,
            hAbf[i & 1], hPbf[i & 1], h1Ab[i & 1], h1Pb[i & 1],
            nodes);
        hAg = hAbf[i & 1]; hPg = hPbf[i & 1];
        h1Ac = h1Ab[i & 1]; h1Pc = h1Pb[i & 1];
    }

    out_mfma<<<(NA + 63) / 64, 256, 0, stream>>>(hAg, Wt2, b2, out, NA);
}

// Round 9
// 392.298 us; speedup vs baseline: 1.2760x; 1.1564x over previous
//
#include <hip/hip_runtime.h>
#include <hip/hip_bf16.h>

#define HOPS 3
#define NA 50000
#define NP 100000
#define NIN 256
#define NHID 128
#define NOUT 64
#define CAP_A 64
#define CAP_P 40

typedef __attribute__((ext_vector_type(8))) short bf16x8;
typedef __attribute__((ext_vector_type(4))) float f32x4;
typedef unsigned short ushort_t;

__device__ inline short f2bf(float f) {
    __hip_bfloat16 h = __float2bfloat16(f);
    return *reinterpret_cast<short*>(&h);
}
__device__ inline float bf2f(unsigned short u) {
    unsigned v = ((unsigned)u) << 16;
    return __uint_as_float(v);
}

// async global -> LDS, 16 bytes per lane (linear dest: base + lane*16)
__device__ inline void gload16(const void* g, void* l) {
    __builtin_amdgcn_global_load_lds(
        (const __attribute__((address_space(1))) unsigned int*)g,
        (__attribute__((address_space(3))) unsigned int*)l, 16, 0, 0);
}

// ---------- all weight transposes+converts in one launch ----------
__global__ void prep_all(const float* __restrict__ W1_A, const float* __restrict__ W1_P,
                         const float* __restrict__ W2,
                         short* __restrict__ WtA, short* __restrict__ WtP,
                         short* __restrict__ Wt2)
{
    int idx = blockIdx.x * 256 + threadIdx.x;
    const int S1 = NHID * NIN;
    if (idx < S1) {
        int n = idx / NIN, k = idx - n * NIN;
        WtA[idx] = f2bf(W1_A[(size_t)k * NHID + n]);
    } else if (idx < 2 * S1) {
        int j = idx - S1;
        int n = j / NIN, k = j - n * NIN;
        WtP[j] = f2bf(W1_P[(size_t)k * NHID + n]);
    } else if (idx < 2 * S1 + NOUT * NHID) {
        int j = idx - 2 * S1;
        int n = j / NHID, k = j - n * NHID;
        Wt2[j] = f2bf(W2[(size_t)k * NOUT + n]);
    }
}

// ---------- projection (round-2 measured-best structure) ----------
__global__ __launch_bounds__(256) void proj_mfma(const float* __restrict__ A,
                                                 const short* __restrict__ Wt,
                                                 const float* __restrict__ b,
                                                 ushort_t* __restrict__ Cbf, int M)
{
    __shared__ short Alds[64][40];
    __shared__ short Wlds[128][40];
    int tid = threadIdx.x;
    int br = blockIdx.x * 64;
    int wv = tid >> 6;
    int l = tid & 63;
    int fl = l & 15;
    int kg = l >> 4;

    int sr = tid >> 2;
    int skp = (tid & 3) * 8;
    int sgr = br + sr; if (sgr >= M) sgr = M - 1;
    int sn = tid >> 1;
    int skq = (tid & 1) * 16;

    f32x4 acc[8];
    #pragma unroll
    for (int c = 0; c < 8; ++c) acc[c] = (f32x4){0.f, 0.f, 0.f, 0.f};

    for (int k0 = 0; k0 < NIN; k0 += 32) {
        const float4* ap = (const float4*)(A + (size_t)sgr * NIN + k0 + skp);
        float4 v0 = ap[0], v1 = ap[1];
        union { short s[8]; int4 v; } pk;
        pk.s[0] = f2bf(v0.x); pk.s[1] = f2bf(v0.y);
        pk.s[2] = f2bf(v0.z); pk.s[3] = f2bf(v0.w);
        pk.s[4] = f2bf(v1.x); pk.s[5] = f2bf(v1.y);
        pk.s[6] = f2bf(v1.z); pk.s[7] = f2bf(v1.w);
        *(int4*)&Alds[sr][skp] = pk.v;
        const int4* wp = (const int4*)(Wt + (size_t)sn * NIN + k0 + skq);
        int4 w0 = wp[0], w1 = wp[1];
        *(int4*)&Wlds[sn][skq] = w0;
        *(int4*)&Wlds[sn][skq + 8] = w1;
        __syncthreads();

        bf16x8 afr = *(bf16x8*)&Alds[wv * 16 + fl][kg * 8];
        #pragma unroll
        for (int c = 0; c < 8; ++c) {
            bf16x8 bfr = *(bf16x8*)&Wlds[c * 16 + fl][kg * 8];
            acc[c] = __builtin_amdgcn_mfma_f32_16x16x32_bf16(afr, bfr, acc[c], 0, 0, 0);
        }
        __syncthreads();
    }

    int rj = kg * 4;
    #pragma unroll
    for (int c = 0; c < 8; ++c) {
        int col = c * 16 + fl;
        float bb = b[col];
        #pragma unroll
        for (int j = 0; j < 4; ++j) {
            int grow = br + wv * 16 + rj + j;
            if (grow < M) {
                float v = fmaxf(acc[c][j] + bb, 0.f);
                Cbf[(size_t)grow * NHID + col] = (ushort_t)f2bf(v);
            }
        }
    }
}

// ---------- output: C[M,64] = Abf[M,128] @ W2 + b2, single-stage MFMA ----------
__global__ __launch_bounds__(256) void out_mfma(const ushort_t* __restrict__ Abf,
        const short* __restrict__ Wt, const float* __restrict__ b,
        float* __restrict__ C, int M)
{
    __shared__ ushort_t Sb[64 * 128];
    const int tid = threadIdx.x;
    const int wv = tid >> 6, l = tid & 63;
    const int fl = l & 15, kg = l >> 4;
    const int br = blockIdx.x * 64;
    const int srow = l >> 4, schk = l & 15;

    #pragma unroll
    for (int i = 0; i < 4; ++i) {
        int r = (wv * 4 + i) * 4 + srow;
        int gr = br + r; if (gr >= M) gr = M - 1;
        int ck = (schk ^ (r & 7)) * 8;
        gload16(Abf + (size_t)gr * NHID + ck, &Sb[(wv * 4 + i) * 512]);
    }

    f32x4 acc[4];
    #pragma unroll
    for (int c = 0; c < 4; ++c) acc[c] = (f32x4){0.f, 0.f, 0.f, 0.f};

    bf16x8 Bf[16];
    #pragma unroll
    for (int ks = 0; ks < 4; ++ks)
        #pragma unroll
        for (int cc = 0; cc < 4; ++cc)
            Bf[ks * 4 + cc] = *(const bf16x8*)(Wt + (size_t)(cc * 16 + fl) * NHID
                                               + ks * 32 + kg * 8);
    __syncthreads();

    const int R = wv * 16 + fl;
    const int rx = R & 7;
    #pragma unroll
    for (int ks = 0; ks < 4; ++ks) {
        int chunk = (ks * 4 + kg) ^ rx;
        bf16x8 af = *(const bf16x8*)&Sb[R * 128 + chunk * 8];
        #pragma unroll
        for (int cc = 0; cc < 4; ++cc)
            acc[cc] = __builtin_amdgcn_mfma_f32_16x16x32_bf16(af, Bf[ks * 4 + cc],
                                                              acc[cc], 0, 0, 0);
    }

    #pragma unroll
    for (int cc = 0; cc < 4; ++cc) {
        int col = cc * 16 + fl;
        float bb = b[col];
        #pragma unroll
        for (int j = 0; j < 4; ++j) {
            int grow = br + wv * 16 + kg * 4 + j;
            if (grow < M) C[(size_t)grow * NOUT + col] = acc[cc][j] + bb;
        }
    }
}

// ---------- merged padded-CSR fill ----------
__global__ void fill_kernel(const int* __restrict__ sA, const int* __restrict__ tA,
                            const int* __restrict__ sP, const int* __restrict__ tP,
                            int* __restrict__ cntA, int* __restrict__ slotsA,
                            int* __restrict__ cntP, int* __restrict__ slotsP, int nE)
{
    int e = blockIdx.x * 256 + threadIdx.x;
    if (e < nE) {
        int si = sA[e];
        int c = atomicAdd(&cntA[si], 1);
        if (c < CAP_A) slotsA[(size_t)si * CAP_A + c] = tA[e];
    } else if (e < 2 * nE) {
        int k = e - nE;
        int si = sP[k];
        int c = atomicAdd(&cntP[si], 1);
        if (c < CAP_P) slotsP[(size_t)si * CAP_P + c] = tP[k];
    }
}

// ---------- merged x-side scalars for ALL hops ----------
__global__ void xdots_kernel(const ushort_t* __restrict__ xAbf, const ushort_t* __restrict__ xPbf,
                             const float* __restrict__ attn1, const float* __restrict__ attn2,
                             float* __restrict__ x1A, float* __restrict__ w2A, float* __restrict__ h1Ai,
                             float* __restrict__ x1P, float* __restrict__ w2P, float* __restrict__ h1Pi)
{
    int wid = (blockIdx.x * blockDim.x + threadIdx.x) >> 6;
    int lane = threadIdx.x & 63;
    if (wid >= NA + NP) return;
    bool isA = wid < NA;
    int n = isA ? wid : wid - NA;
    int etype = isA ? 0 : 1;
    const ushort_t* x = (isA ? xAbf : xPbf) + (size_t)n * NHID;
    ushort2 xv = *(const ushort2*)(x + lane * 2);
    float xa = bf2f(xv.x), xb = bf2f(xv.y);
    float s[7];
    #pragma unroll
    for (int i = 0; i < 3; ++i) {
        float2 a1v = *(const float2*)(attn1 + (size_t)(i * 2 + etype) * NHID + lane * 2);
        float2 a2v = *(const float2*)(attn2 + (size_t)(i * 2 + etype) * NHID + lane * 2);
        s[i]     = xa * a1v.x + xb * a1v.y;
        s[3 + i] = xa * a2v.x + xb * a2v.y;
    }
    float2 a2o = *(const float2*)(attn2 + (size_t)(1 - etype) * NHID + lane * 2);
    s[6] = xa * a2o.x + xb * a2o.y;
    #pragma unroll
    for (int m = 32; m; m >>= 1)
        #pragma unroll
        for (int i = 0; i < 7; ++i) s[i] += __shfl_xor(s[i], m, 64);
    if (lane == 0) {
        int N = isA ? NA : NP;
        float* x1 = isA ? x1A : x1P;
        float* w2 = isA ? w2A : w2P;
        #pragma unroll
        for (int i = 0; i < 3; ++i) {
            x1[(size_t)i * N + n] = s[i];
            float v = s[i] + s[3 + i];
            v = v > 0.f ? v : 0.2f * v;
            w2[(size_t)i * N + n] = __expf(v);
        }
        (isA ? h1Ai : h1Pi)[n] = s[6];
    }
}

// ---------- fused A+P aggregation: 16 feature-lanes x 4 edge-groups ----------
// Wave-cooperative preload of all (t,w); inner loop 1 int4 per lane per edge
// (fl owns 8 features); xor-butterfly leaves FULL sums in every lane, so the
// epilogue is split across groups: each lane finishes exactly 2 features.
__global__ __launch_bounds__(256) void agg_fused(
    const ushort_t* __restrict__ xAbf, const ushort_t* __restrict__ xPbf,
    const ushort_t* __restrict__ hAg, const ushort_t* __restrict__ hPg,
    const float* __restrict__ x1Ah, const float* __restrict__ x1Ph,
    const float* __restrict__ w2Ah, const float* __restrict__ w2Ph,
    const float* __restrict__ h1Agc, const float* __restrict__ h1Pgc,
    const int* __restrict__ cntA, const int* __restrict__ slotsA,
    const int* __restrict__ cntP, const int* __restrict__ slotsP,
    const float* __restrict__ a2nA, const float* __restrict__ a2nP,
    ushort_t* __restrict__ hAout, ushort_t* __restrict__ hPout,
    float* __restrict__ h1Aout, float* __restrict__ h1Pout,
    int nodes)
{
    int wid = (blockIdx.x * blockDim.x + threadIdx.x) >> 6;
    int lane = threadIdx.x & 63;
    if (wid >= nodes) return;
    int g = lane >> 4, fl = lane & 15;
    bool isA = wid < NA;
    int n = isA ? wid : wid - NA;
    int deg; const int* sl; const ushort_t* hbf; const float* h1g; float x1v;
    if (isA) {
        deg = cntA[n]; if (deg > CAP_A) deg = CAP_A;
        sl = slotsA + (size_t)n * CAP_A; hbf = hPg; h1g = h1Pgc; x1v = x1Ah[n];
    } else {
        deg = cntP[n]; if (deg > CAP_P) deg = CAP_P;
        sl = slotsP + (size_t)n * CAP_P; hbf = hAg; h1g = h1Agc; x1v = x1Ph[n];
    }

    // cooperative preload: lane l holds edge l's (t, w)
    int t_l = 0;
    float w_l = 0.f;
    if (deg > 0) {
        int idx = lane < deg ? lane : deg - 1;
        t_l = sl[idx];
        if (lane < deg) {
            float v = x1v + h1g[t_l];
            v = v > 0.f ? v : 0.2f * v;
            w_l = __expf(v);
        }
    }
    float div = w_l;
    #pragma unroll
    for (int m = 1; m <= 32; m <<= 1) div += __shfl_xor(div, m, 64);

    float acc[8] = {};
    int R = (deg + 3) >> 2;

    int4 ra = {0, 0, 0, 0};
    if (R > 0) {
        int t0 = __shfl(t_l, g, 64);
        ra = *(const int4*)(hbf + (size_t)t0 * NHID + fl * 8);
    }
    for (int r = 0; r < R; ++r) {
        float w = __shfl(w_l, r * 4 + g, 64);
        int4 cur = ra;
        if (r + 1 < R) {
            int tn = __shfl(t_l, (r + 1) * 4 + g, 64);
            ra = *(const int4*)(hbf + (size_t)tn * NHID + fl * 8);
        }
        unsigned q0 = (unsigned)cur.x, q1 = (unsigned)cur.y;
        unsigned q2 = (unsigned)cur.z, q3 = (unsigned)cur.w;
        acc[0] += w * __uint_as_float(q0 << 16);
        acc[1] += w * __uint_as_float(q0 & 0xffff0000u);
        acc[2] += w * __uint_as_float(q1 << 16);
        acc[3] += w * __uint_as_float(q1 & 0xffff0000u);
        acc[4] += w * __uint_as_float(q2 << 16);
        acc[5] += w * __uint_as_float(q2 & 0xffff0000u);
        acc[6] += w * __uint_as_float(q3 << 16);
        acc[7] += w * __uint_as_float(q3 & 0xffff0000u);
    }
    // combine the 4 groups; afterwards EVERY lane holds full sums for its fl
    #pragma unroll
    for (int m = 16; m <= 32; m <<= 1) {
        #pragma unroll
        for (int j = 0; j < 8; ++j) acc[j] += __shfl_xor(acc[j], m, 64);
    }

    // all-lane epilogue: lane (g,fl) finishes features fl*8 + 2g, 2g+1
    float alo = (g == 0) ? acc[0] : (g == 1) ? acc[2] : (g == 2) ? acc[4] : acc[6];
    float ahi = (g == 0) ? acc[1] : (g == 1) ? acc[3] : (g == 2) ? acc[5] : acc[7];

    float w2v = isA ? w2Ah[n] : w2Ph[n];
    const ushort_t* xb = (isA ? xAbf : xPbf) + (size_t)n * NHID;
    unsigned xq = *(const unsigned*)(xb + fl * 8 + 2 * g);
    alo += w2v * __uint_as_float(xq << 16);
    ahi += w2v * __uint_as_float(xq & 0xffff0000u);
    float dv = div + w2v;
    float inv = 1.f / dv;
    float vlo = alo * inv, vhi = ahi * inv;
    float olo = vlo > 0.f ? vlo : (__expf(vlo) - 1.f);
    float ohi = vhi > 0.f ? vhi : (__expf(vhi) - 1.f);

    // next-hop h1 dot (full-wave)
    const float* a2 = isA ? a2nA : a2nP;
    float2 av = *(const float2*)(a2 + fl * 8 + 2 * g);
    float s = olo * av.x + ohi * av.y;
    #pragma unroll
    for (int m = 1; m <= 32; m <<= 1) s += __shfl_xor(s, m, 64);

    // packed store: one u32 (2 bf16) per lane = full 256B row per wave
    unsigned plo = ((unsigned)(ushort_t)f2bf(olo));
    unsigned phi = ((unsigned)(ushort_t)f2bf(ohi)) << 16;
    unsigned* hb = (unsigned*)((isA ? hAout : hPout) + (size_t)n * NHID);
    hb[fl * 4 + g] = plo | phi;
    if (lane == 0) (isA ? h1Aout : h1Pout)[n] = s;
}

extern "C" void kernel_launch(void* const* d_in, const int* in_sizes, int n_in,
                              void* d_out, int out_size, void* d_ws, size_t ws_size,
                              hipStream_t stream)
{
    const float* x_A  = (const float*)d_in[0];
    const float* x_P  = (const float*)d_in[1];
    const int*   sAP  = (const int*)d_in[2];
    const int*   tAP  = (const int*)d_in[3];
    const int*   sPA  = (const int*)d_in[4];
    const int*   tPA  = (const int*)d_in[5];
    const float* W1_A = (const float*)d_in[6];
    const float* b1_A = (const float*)d_in[7];
    const float* W1_P = (const float*)d_in[8];
    const float* b1_P = (const float*)d_in[9];
    const float* attn1 = (const float*)d_in[10];
    const float* attn2 = (const float*)d_in[11];
    const float* W2   = (const float*)d_in[12];
    const float* b2   = (const float*)d_in[13];
    float* out = (float*)d_out;
    int nE = in_sizes[2];

    char* ws = (char*)d_ws;
    size_t off = 0;
    auto alloc = [&](size_t bytes) -> void* {
        void* p = ws + off;
        off += (bytes + 255) & ~(size_t)255;
        return p;
    };
    ushort_t* xAbf  = (ushort_t*)alloc((size_t)NA * NHID * 2);
    ushort_t* xPbf  = (ushort_t*)alloc((size_t)NP * NHID * 2);
    ushort_t* hAbf[2] = {(ushort_t*)alloc((size_t)NA * NHID * 2),
                         (ushort_t*)alloc((size_t)NA * NHID * 2)};
    ushort_t* hPbf[2] = {(ushort_t*)alloc((size_t)NP * NHID * 2),
                         (ushort_t*)alloc((size_t)NP * NHID * 2)};
    float* x1A = (float*)alloc((size_t)3 * NA * 4);
    float* w2A = (float*)alloc((size_t)3 * NA * 4);
    float* x1P = (float*)alloc((size_t)3 * NP * 4);
    float* w2P = (float*)alloc((size_t)3 * NP * 4);
    float* h1Ai = (float*)alloc(NA * 4);
    float* h1Pi = (float*)alloc(NP * 4);
    float* h1Ab[2] = {(float*)alloc(NA * 4), (float*)alloc(NA * 4)};
    float* h1Pb[2] = {(float*)alloc(NP * 4), (float*)alloc(NP * 4)};
    int* cntA  = (int*)alloc(NA * 4);
    int* cntP  = (int*)alloc(NP * 4);
    int* slotsA = (int*)alloc((size_t)NA * CAP_A * 4);
    int* slotsP = (int*)alloc((size_t)NP * CAP_P * 4);
    short* WtA = (short*)alloc((size_t)NHID * NIN * 2);
    short* WtP = (short*)alloc((size_t)NHID * NIN * 2);
    short* Wt2 = (short*)alloc((size_t)NOUT * NHID * 2);

    // padded CSR (edge structure reused by all hops)
    hipMemsetAsync(cntA, 0, NA * 4, stream);
    hipMemsetAsync(cntP, 0, NP * 4, stream);
    fill_kernel<<<(2 * nE + 255) / 256, 256, 0, stream>>>(sAP, tAP, sPA, tPA,
                                                          cntA, slotsA, cntP, slotsP, nE);

    // weights -> bf16 transposed (one launch)
    prep_all<<<(2 * NHID * NIN + NOUT * NHID + 255) / 256, 256, 0, stream>>>(
        W1_A, W1_P, W2, WtA, WtP, Wt2);

    // projections -> bf16 h0 (round-2 measured-best structure)
    proj_mfma<<<(NA + 63) / 64, 256, 0, stream>>>(x_A, WtA, b1_A, xAbf, NA);
    proj_mfma<<<(NP + 63) / 64, 256, 0, stream>>>(x_P, WtP, b1_P, xPbf, NP);

    // x-side scalars for all hops (merged)
    xdots_kernel<<<(NA + NP + 3) / 4, 256, 0, stream>>>(
        xAbf, xPbf, attn1, attn2, x1A, w2A, h1Ai, x1P, w2P, h1Pi);

    const ushort_t* hAg = xAbf;
    const ushort_t* hPg = xPbf;
    const float* h1Ac = h1Ai;
    const float* h1Pc = h1Pi;

    for (int i = 0; i < HOPS; ++i) {
        int last = (i == HOPS - 1);
        int nodes = last ? NA : (NA + NP);
        const float* a2nA_ = last ? attn2 : attn2 + (size_t)((i + 1) * 2 + 1) * NHID;
        const float* a2nP_ = last ? attn2 : attn2 + (size_t)((i + 1) * 2 + 0) * NHID;
        agg_fused<<<(nodes + 3) / 4, 256, 0, stream>>>(
            xAbf, xPbf, hAg, hPg,
            x1A + (size_t)i * NA, x1P + (size_t)i * NP,
            w2A + (size_t)i * NA, w2P + (size_t)i * NP,
            h1Ac, h1Pc,
            cntA, slotsA, cntP, slotsP,
            a2nA_, a2nP_,
            hAbf[i & 1], hPbf[i & 1], h1Ab[i & 1], h1Pb[i & 1],
            nodes);
        hAg = hAbf[i & 1]; hPg = hPbf[i & 1];
        h1Ac = h1Ab[i & 1]; h1Pc = h1Pb[i & 1];
    }

    out_mfma<<<(NA + 63) / 64, 256, 0, stream>>>(hAg, Wt2, b2, out, NA);
}